// Round 3
// baseline (1699.595 us; speedup 1.0000x reference)
//
#include <hip/hip_runtime.h>
#include <math.h>

typedef unsigned int u32;
typedef unsigned short u16;

// ---------------------------------------------------------------------------
// Graph TransformerConv x3 (PyG semantics).
//   CSR build (deg -> two-level scan -> scatter), reused by all 3 layers.
//   Per layer: kv staged bf16 channel-interleaved [n][c][k0,k1,k2,v0,v1,v2];
//   attention kernel computes q + skip projections inline (one wave per node),
//   online softmax, epilogue fused (mean heads + skip + relu + resid).
//   Layer 3: kv3 staged f32 [n][20]; attn computes q3/s3 inline, fuses
//   skip-add + log_softmax.
//   Fallback path (small ws): recompute k,v per edge from h and W.
// ---------------------------------------------------------------------------

__device__ __forceinline__ float bf2f(u16 u) {
  union { u32 i; float f; } c; c.i = ((u32)u) << 16; return c.f;
}
__device__ __forceinline__ u16 f2bf(float f) {
  union { float f; u32 i; } c; c.f = f;
  u32 u = c.i;
  u32 r = u + 0x7fffu + ((u >> 16) & 1u);  // round-to-nearest-even
  return (u16)(r >> 16);
}

__global__ __launch_bounds__(256) void zero_i32_kernel(int* __restrict__ p, int n) {
  int i = blockIdx.x * blockDim.x + threadIdx.x;
  if (i < n) p[i] = 0;
}

__global__ __launch_bounds__(256) void deg_kernel(
    const int* __restrict__ dst, int* __restrict__ deg, int E) {
  int e = blockIdx.x * blockDim.x + threadIdx.x;
  if (e < E) atomicAdd(&deg[dst[e]], 1);
}

// per-block (1024) exclusive scan; writes per-elem exclusive + block sum
__global__ __launch_bounds__(1024) void scan1_kernel(
    const int* __restrict__ deg, int* __restrict__ excl,
    int* __restrict__ bsum, int n) {
  __shared__ int wsum[16];
  int tid = threadIdx.x;
  int i = blockIdx.x * 1024 + tid;
  int v = (i < n) ? deg[i] : 0;
  int lane = tid & 63, w = tid >> 6;
  int val = v;
#pragma unroll
  for (int off = 1; off < 64; off <<= 1) {
    int t = __shfl_up(val, off, 64);
    if (lane >= off) val += t;
  }
  if (lane == 63) wsum[w] = val;
  __syncthreads();
  if (tid < 16) {
    int xv = wsum[tid];
    int xs = xv;
#pragma unroll
    for (int off = 1; off < 16; off <<= 1) {
      int t = __shfl_up(xs, off, 16);
      if (tid >= off) xs += t;
    }
    wsum[tid] = xs - xv;  // exclusive wave offset
  }
  __syncthreads();
  int incl = val + wsum[w];
  if (i < n) excl[i] = incl - v;
  if (tid == 1023) bsum[blockIdx.x] = incl;
}

// single block: in-place exclusive scan of nb (<=1024) block sums
__global__ __launch_bounds__(1024) void scan2_kernel(int* __restrict__ bsum, int nb) {
  __shared__ int wsum[16];
  int tid = threadIdx.x;
  int v = (tid < nb) ? bsum[tid] : 0;
  int lane = tid & 63, w = tid >> 6;
  int val = v;
#pragma unroll
  for (int off = 1; off < 64; off <<= 1) {
    int t = __shfl_up(val, off, 64);
    if (lane >= off) val += t;
  }
  if (lane == 63) wsum[w] = val;
  __syncthreads();
  if (tid < 16) {
    int xv = wsum[tid];
    int xs = xv;
#pragma unroll
    for (int off = 1; off < 16; off <<= 1) {
      int t = __shfl_up(xs, off, 16);
      if (tid >= off) xs += t;
    }
    wsum[tid] = xs - xv;
  }
  __syncthreads();
  int incl = val + wsum[w];
  if (tid < nb) bsum[tid] = incl - v;
}

__global__ __launch_bounds__(256) void scan3_kernel(
    const int* __restrict__ excl, const int* __restrict__ bsum,
    int* __restrict__ rowptr, int* __restrict__ cursor, int n, int E) {
  int i = blockIdx.x * blockDim.x + threadIdx.x;
  if (i < n) {
    int r = excl[i] + bsum[i >> 10];
    rowptr[i] = r;
    cursor[i] = r;
  }
  if (i == n) rowptr[n] = E;
}

__global__ __launch_bounds__(256) void scatter_kernel(
    const int* __restrict__ src, const int* __restrict__ dst,
    int* __restrict__ cursor, int* __restrict__ csr_src, int E) {
  int e = blockIdx.x * blockDim.x + threadIdx.x;
  if (e < E) {
    int pos = atomicAdd(&cursor[dst[e]], 1);
    csr_src[pos] = src[e];
  }
}

// k/v projection -> bf16 kv, channel-interleaved: kv[n*384 + c*6 + which*3 + h]
template<int FI, bool XBF>
__global__ __launch_bounds__(256) void kv_proj_kernel(
    const void* __restrict__ xin,
    const float* __restrict__ Wk, const float* __restrict__ bk,
    const float* __restrict__ Wv, const float* __restrict__ bv,
    u16* __restrict__ kv, int n_nodes) {
  int idx = blockIdx.x * blockDim.x + threadIdx.x;
  if (idx >= n_nodes * 384) return;
  int n = idx / 384;
  int r = idx - n * 384;
  int which = r / 192;          // 0=k 1=v
  int o = r - which * 192;
  const float* W = which ? Wv : Wk;
  float acc = (which ? bv : bk)[o];
  if (XBF) {
    const u16* xr = (const u16*)xin + (size_t)n * FI;
#pragma unroll
    for (int i = 0; i < FI; ++i) acc = fmaf(bf2f(xr[i]), W[i * 192 + o], acc);
  } else {
    const float* xr = (const float*)xin + (size_t)n * FI;
#pragma unroll
    for (int i = 0; i < FI; ++i) acc = fmaf(xr[i], W[i * 192 + o], acc);
  }
  int h = o >> 6, c = o & 63;
  kv[(size_t)n * 384 + c * 6 + which * 3 + h] = f2bf(acc);
}

// Fused attention, H=3, C=64, one wave per dst node, q+skip computed inline.
// STAGED: gather bf16 kv (12B contiguous per lane). !STAGED: recompute k,v per
// edge from xin and Wk/Wv (low-memory fallback).
template<int FI, bool XBF, bool STAGED>
__global__ __launch_bounds__(256) void attn_l12_kernel(
    const void* __restrict__ xin,
    const float* __restrict__ Wq, const float* __restrict__ bq,
    const float* __restrict__ Ws, const float* __restrict__ bs,
    const float* __restrict__ Wk, const float* __restrict__ bk,
    const float* __restrict__ Wv, const float* __restrict__ bv,
    const u16* __restrict__ kv,
    const int* __restrict__ rowptr, const int* __restrict__ csr_src,
    const u16* __restrict__ resid,  // null for layer 1
    u16* __restrict__ hout, int n_nodes) {
  int wid = (blockIdx.x * blockDim.x + threadIdx.x) >> 6;
  int lane = threadIdx.x & 63;
  if (wid >= n_nodes) return;
  // inline q + skip projection for this node
  float q0 = bq[lane], q1 = bq[64 + lane], q2 = bq[128 + lane];
  float sk = bs[lane];
  {
    const u16* xb = (const u16*)xin + (size_t)wid * FI;
    const float* xf = (const float*)xin + (size_t)wid * FI;
#pragma unroll 4
    for (int i = 0; i < FI; ++i) {
      float xi = XBF ? bf2f(xb[i]) : xf[i];
      q0 = fmaf(xi, Wq[i * 192 + lane], q0);
      q1 = fmaf(xi, Wq[i * 192 + 64 + lane], q1);
      q2 = fmaf(xi, Wq[i * 192 + 128 + lane], q2);
      sk = fmaf(xi, Ws[i * 64 + lane], sk);
    }
  }
  const float scale = 0.125f;  // 1/sqrt(64)
  q0 *= scale; q1 *= scale; q2 *= scale;
  float m0 = -INFINITY, m1 = -INFINITY, m2 = -INFINITY;
  float s0 = 0.f, s1 = 0.f, s2 = 0.f;
  float a0 = 0.f, a1 = 0.f, a2 = 0.f;
  int beg = rowptr[wid], end = rowptr[wid + 1];
  if (STAGED) {
    int e = beg;
    for (; e + 2 <= end; e += 2) {
      int sa = csr_src[e], sb = csr_src[e + 1];
      const u32* pa = (const u32*)(kv + (size_t)sa * 384) + lane * 3;
      const u32* pb = (const u32*)(kv + (size_t)sb * 384) + lane * 3;
      u32 aw0 = pa[0], aw1 = pa[1], aw2 = pa[2];
      u32 bw0 = pb[0], bw1 = pb[1], bw2 = pb[2];
      float ka0 = bf2f((u16)aw0), ka1 = bf2f((u16)(aw0 >> 16)), ka2 = bf2f((u16)aw1);
      float va0 = bf2f((u16)(aw1 >> 16)), va1 = bf2f((u16)aw2), va2 = bf2f((u16)(aw2 >> 16));
      float kb0 = bf2f((u16)bw0), kb1 = bf2f((u16)(bw0 >> 16)), kb2 = bf2f((u16)bw1);
      float vb0 = bf2f((u16)(bw1 >> 16)), vb1 = bf2f((u16)bw2), vb2 = bf2f((u16)(bw2 >> 16));
      float xa0 = q0 * ka0, xa1 = q1 * ka1, xa2 = q2 * ka2;
      float xb0 = q0 * kb0, xb1 = q1 * kb1, xb2 = q2 * kb2;
#pragma unroll
      for (int off = 32; off >= 1; off >>= 1) {
        xa0 += __shfl_xor(xa0, off, 64);
        xa1 += __shfl_xor(xa1, off, 64);
        xa2 += __shfl_xor(xa2, off, 64);
        xb0 += __shfl_xor(xb0, off, 64);
        xb1 += __shfl_xor(xb1, off, 64);
        xb2 += __shfl_xor(xb2, off, 64);
      }
      float nm, sc, wa, wb;
      nm = fmaxf(fmaxf(m0, xa0), xb0);
      sc = __expf(m0 - nm); wa = __expf(xa0 - nm); wb = __expf(xb0 - nm);
      s0 = s0 * sc + wa + wb; a0 = a0 * sc + wa * va0 + wb * vb0; m0 = nm;
      nm = fmaxf(fmaxf(m1, xa1), xb1);
      sc = __expf(m1 - nm); wa = __expf(xa1 - nm); wb = __expf(xb1 - nm);
      s1 = s1 * sc + wa + wb; a1 = a1 * sc + wa * va1 + wb * vb1; m1 = nm;
      nm = fmaxf(fmaxf(m2, xa2), xb2);
      sc = __expf(m2 - nm); wa = __expf(xa2 - nm); wb = __expf(xb2 - nm);
      s2 = s2 * sc + wa + wb; a2 = a2 * sc + wa * va2 + wb * vb2; m2 = nm;
    }
    if (e < end) {
      int sa = csr_src[e];
      const u32* pa = (const u32*)(kv + (size_t)sa * 384) + lane * 3;
      u32 aw0 = pa[0], aw1 = pa[1], aw2 = pa[2];
      float ka0 = bf2f((u16)aw0), ka1 = bf2f((u16)(aw0 >> 16)), ka2 = bf2f((u16)aw1);
      float va0 = bf2f((u16)(aw1 >> 16)), va1 = bf2f((u16)aw2), va2 = bf2f((u16)(aw2 >> 16));
      float xa0 = q0 * ka0, xa1 = q1 * ka1, xa2 = q2 * ka2;
#pragma unroll
      for (int off = 32; off >= 1; off >>= 1) {
        xa0 += __shfl_xor(xa0, off, 64);
        xa1 += __shfl_xor(xa1, off, 64);
        xa2 += __shfl_xor(xa2, off, 64);
      }
      float nm, sc, wa;
      nm = fmaxf(m0, xa0); sc = __expf(m0 - nm); wa = __expf(xa0 - nm);
      s0 = s0 * sc + wa; a0 = a0 * sc + wa * va0; m0 = nm;
      nm = fmaxf(m1, xa1); sc = __expf(m1 - nm); wa = __expf(xa1 - nm);
      s1 = s1 * sc + wa; a1 = a1 * sc + wa * va1; m1 = nm;
      nm = fmaxf(m2, xa2); sc = __expf(m2 - nm); wa = __expf(xa2 - nm);
      s2 = s2 * sc + wa; a2 = a2 * sc + wa * va2; m2 = nm;
    }
  } else {
    for (int e = beg; e < end; ++e) {
      int srcn = csr_src[e];
      float k0 = bk[lane], k1 = bk[64 + lane], k2 = bk[128 + lane];
      float v0 = bv[lane], v1 = bv[64 + lane], v2 = bv[128 + lane];
      const u16* hb = (const u16*)xin + (size_t)srcn * FI;
      const float* hf = (const float*)xin + (size_t)srcn * FI;
#pragma unroll 4
      for (int i = 0; i < FI; ++i) {
        float xi = XBF ? bf2f(hb[i]) : hf[i];
        k0 = fmaf(xi, Wk[i * 192 + lane], k0);
        k1 = fmaf(xi, Wk[i * 192 + 64 + lane], k1);
        k2 = fmaf(xi, Wk[i * 192 + 128 + lane], k2);
        v0 = fmaf(xi, Wv[i * 192 + lane], v0);
        v1 = fmaf(xi, Wv[i * 192 + 64 + lane], v1);
        v2 = fmaf(xi, Wv[i * 192 + 128 + lane], v2);
      }
      float xa0 = q0 * k0, xa1 = q1 * k1, xa2 = q2 * k2;
#pragma unroll
      for (int off = 32; off >= 1; off >>= 1) {
        xa0 += __shfl_xor(xa0, off, 64);
        xa1 += __shfl_xor(xa1, off, 64);
        xa2 += __shfl_xor(xa2, off, 64);
      }
      float nm, sc, wa;
      nm = fmaxf(m0, xa0); sc = __expf(m0 - nm); wa = __expf(xa0 - nm);
      s0 = s0 * sc + wa; a0 = a0 * sc + wa * v0; m0 = nm;
      nm = fmaxf(m1, xa1); sc = __expf(m1 - nm); wa = __expf(xa1 - nm);
      s1 = s1 * sc + wa; a1 = a1 * sc + wa * v1; m1 = nm;
      nm = fmaxf(m2, xa2); sc = __expf(m2 - nm); wa = __expf(xa2 - nm);
      s2 = s2 * sc + wa; a2 = a2 * sc + wa * v2; m2 = nm;
    }
  }
  float val = (a0 / (s0 + 1e-16f) + a1 / (s1 + 1e-16f) + a2 / (s2 + 1e-16f)) *
              (1.0f / 3.0f);
  val += sk;
  val = fmaxf(val, 0.0f);
  if (resid) val += bf2f(resid[(size_t)wid * 64 + lane]);
  hout[(size_t)wid * 64 + lane] = f2bf(val);
}

// layer-3 k/v projection -> f32 kv3 [n][20] = {k(10), v(10)}
__global__ __launch_bounds__(256) void kv3_proj_kernel(
    const u16* __restrict__ h,
    const float* __restrict__ Wk, const float* __restrict__ bk,
    const float* __restrict__ Wv, const float* __restrict__ bv,
    float* __restrict__ kv3, int n_nodes) {
  int idx = blockIdx.x * blockDim.x + threadIdx.x;
  if (idx >= n_nodes * 20) return;
  int n = idx / 20;
  int r = idx - n * 20;
  int which = r / 10;
  int o = r - which * 10;
  const float* W = which ? Wv : Wk;
  float acc = (which ? bv : bk)[o];
  const u16* hr = h + (size_t)n * 64;
#pragma unroll
  for (int i = 0; i < 64; ++i) acc = fmaf(bf2f(hr[i]), W[i * 10 + o], acc);
  kv3[(size_t)n * 20 + which * 10 + o] = acc;
}

// layer-3 attention H=1,C=10 concat + skip + log_softmax; q/skip inline.
// 4 nodes per wave, 16 lanes per node.
__global__ __launch_bounds__(256) void attn_l3_kernel(
    const u16* __restrict__ h,
    const float* __restrict__ Wq, const float* __restrict__ bq,
    const float* __restrict__ Ws, const float* __restrict__ bs,
    const float* __restrict__ kv3,
    const int* __restrict__ rowptr, const int* __restrict__ csr_src,
    float* __restrict__ out, int n_nodes) {
  int tid = blockIdx.x * blockDim.x + threadIdx.x;
  int wid = tid >> 6;
  int lane = threadIdx.x & 63;
  int grp = lane >> 4;
  int sub = lane & 15;
  int n = wid * 4 + grp;
  bool an = (n < n_nodes);
  bool ca = an && (sub < 10);
  float q = 0.f, sk = 0.f;
  if (ca) { q = bq[sub]; sk = bs[sub]; }
  if (an) {
    const u16* hr = h + (size_t)n * 64;
#pragma unroll 4
    for (int i = 0; i < 64; ++i) {
      float xi = bf2f(hr[i]);
      if (sub < 10) {
        q = fmaf(xi, Wq[i * 10 + sub], q);
        sk = fmaf(xi, Ws[i * 10 + sub], sk);
      }
    }
  }
  q *= 0.31622776601683794f;  // 1/sqrt(10)
  float m = -INFINITY, s = 0.f, a = 0.f;
  int beg = 0, end = 0;
  if (an) { beg = rowptr[n]; end = rowptr[n + 1]; }
  for (int e = beg; e < end; ++e) {
    int srcn = csr_src[e];
    float kk = (sub < 10) ? kv3[(size_t)srcn * 20 + sub] : 0.f;
    float vv = (sub < 10) ? kv3[(size_t)srcn * 20 + 10 + sub] : 0.f;
    float p = q * kk;
    p += __shfl_xor(p, 1, 64);
    p += __shfl_xor(p, 2, 64);
    p += __shfl_xor(p, 4, 64);
    p += __shfl_xor(p, 8, 64);
    float nm = fmaxf(m, p);
    float sc = __expf(m - nm);
    float w = __expf(p - nm);
    s = s * sc + w;
    a = a * sc + w * vv;
    m = nm;
  }
  float z = 0.f;
  if (ca) z = a / (s + 1e-16f) + sk;
  float zm = (sub < 10) ? z : -INFINITY;
  float t;
  t = __shfl_xor(zm, 1, 64); zm = fmaxf(zm, t);
  t = __shfl_xor(zm, 2, 64); zm = fmaxf(zm, t);
  t = __shfl_xor(zm, 4, 64); zm = fmaxf(zm, t);
  t = __shfl_xor(zm, 8, 64); zm = fmaxf(zm, t);
  float ez = (sub < 10) ? __expf(z - zm) : 0.f;
  float se = ez;
  se += __shfl_xor(se, 1, 64);
  se += __shfl_xor(se, 2, 64);
  se += __shfl_xor(se, 4, 64);
  se += __shfl_xor(se, 8, 64);
  float ls = logf(se);
  if (ca) out[(size_t)n * 10 + sub] = (z - zm) - ls;
}

extern "C" void kernel_launch(void* const* d_in, const int* in_sizes, int n_in,
                              void* d_out, int out_size, void* d_ws, size_t ws_size,
                              hipStream_t stream) {
  const float* x = (const float*)d_in[0];
  const int* ei = (const int*)d_in[1];
  const int N = in_sizes[0] / 13;
  const int E = in_sizes[1] / 2;
  const int* esrc = ei;
  const int* edst = ei + E;

  const float* q1w = (const float*)d_in[2];  const float* q1b = (const float*)d_in[3];
  const float* k1w = (const float*)d_in[4];  const float* k1b = (const float*)d_in[5];
  const float* v1w = (const float*)d_in[6];  const float* v1b = (const float*)d_in[7];
  const float* s1w = (const float*)d_in[8];  const float* s1b = (const float*)d_in[9];
  const float* q2w = (const float*)d_in[10]; const float* q2b = (const float*)d_in[11];
  const float* k2w = (const float*)d_in[12]; const float* k2b = (const float*)d_in[13];
  const float* v2w = (const float*)d_in[14]; const float* v2b = (const float*)d_in[15];
  const float* s2w = (const float*)d_in[16]; const float* s2b = (const float*)d_in[17];
  const float* q3w = (const float*)d_in[18]; const float* q3b = (const float*)d_in[19];
  const float* k3w = (const float*)d_in[20]; const float* k3b = (const float*)d_in[21];
  const float* v3w = (const float*)d_in[22]; const float* v3b = (const float*)d_in[23];
  const float* s3w = (const float*)d_in[24]; const float* s3b = (const float*)d_in[25];

  // ---- workspace carve-up; staged kv LAST so the fallback needs less ----
  size_t off = 0;
  auto carve = [&](size_t bytes) {
    void* p = (char*)d_ws + off;
    off += (bytes + 255) & ~(size_t)255;
    return p;
  };
  int* deg    = (int*)carve((size_t)N * 4);
  int* excl   = (int*)carve((size_t)N * 4);
  int* bsum   = (int*)carve(4096);
  int* rowptr = (int*)carve((size_t)(N + 1) * 4);
  int* cursor = (int*)carve((size_t)N * 4);
  int* csr    = (int*)carve((size_t)E * 4);
  u16* h1     = (u16*)carve((size_t)N * 64 * 2);
  u16* h2     = (u16*)carve((size_t)N * 64 * 2);
  float* kv3  = (float*)carve((size_t)N * 20 * 4);
  size_t need_common = off;
  u16* kv     = (u16*)carve((size_t)N * 384 * 2);
  size_t need_staged = off;
  bool staged = (ws_size >= need_staged);
  if (!staged && ws_size < need_common) return;  // cannot run at all

  // ---- CSR build ----
  int nb = (N + 1023) / 1024;
  zero_i32_kernel<<<(N + 255) / 256, 256, 0, stream>>>(deg, N);
  deg_kernel<<<(E + 255) / 256, 256, 0, stream>>>(edst, deg, E);
  scan1_kernel<<<nb, 1024, 0, stream>>>(deg, excl, bsum, N);
  scan2_kernel<<<1, 1024, 0, stream>>>(bsum, nb);
  scan3_kernel<<<(N + 1 + 255) / 256, 256, 0, stream>>>(excl, bsum, rowptr, cursor, N, E);
  scatter_kernel<<<(E + 255) / 256, 256, 0, stream>>>(esrc, edst, cursor, csr, E);

  int attn_blocks = (N + 3) / 4;  // one wave per node, 4 waves per block
  // ---- layer 1: x(f32)[N,13] -> h1(bf16)[N,64] ----
  if (staged) {
    kv_proj_kernel<13, false><<<(N * 384 + 255) / 256, 256, 0, stream>>>(
        x, k1w, k1b, v1w, v1b, kv, N);
    attn_l12_kernel<13, false, true><<<attn_blocks, 256, 0, stream>>>(
        x, q1w, q1b, s1w, s1b, k1w, k1b, v1w, v1b, kv, rowptr, csr, nullptr, h1, N);
  } else {
    attn_l12_kernel<13, false, false><<<attn_blocks, 256, 0, stream>>>(
        x, q1w, q1b, s1w, s1b, k1w, k1b, v1w, v1b, nullptr, rowptr, csr, nullptr, h1, N);
  }
  // ---- layer 2: h1 -> h2 = relu(conv2(h1)) + h1 ----
  if (staged) {
    kv_proj_kernel<64, true><<<(N * 384 + 255) / 256, 256, 0, stream>>>(
        h1, k2w, k2b, v2w, v2b, kv, N);
    attn_l12_kernel<64, true, true><<<attn_blocks, 256, 0, stream>>>(
        h1, q2w, q2b, s2w, s2b, k2w, k2b, v2w, v2b, kv, rowptr, csr, h1, h2, N);
  } else {
    attn_l12_kernel<64, true, false><<<attn_blocks, 256, 0, stream>>>(
        h1, q2w, q2b, s2w, s2b, k2w, k2b, v2w, v2b, nullptr, rowptr, csr, h1, h2, N);
  }
  // ---- layer 3: h2 -> out[N,10] + log_softmax ----
  kv3_proj_kernel<<<(N * 20 + 255) / 256, 256, 0, stream>>>(
      h2, k3w, k3b, v3w, v3b, kv3, N);
  attn_l3_kernel<<<(N + 15) / 16, 256, 0, stream>>>(
      h2, q3w, q3b, s3w, s3b, kv3, rowptr, csr, (float*)d_out, N);
}

// Round 7
// 1383.837 us; speedup vs baseline: 1.2282x; 1.2282x over previous
//
#include <hip/hip_runtime.h>
#include <math.h>

typedef unsigned int u32;
typedef unsigned short u16;

// ---------------------------------------------------------------------------
// Graph TransformerConv x3 (PyG semantics).
//   CSR build (deg -> two-level scan -> scatter), reused by all 3 layers.
//   Per layer: kv staged bf16 channel-interleaved [n][c][k0,k1,k2,v0,v1,v2]
//   via LDS-tiled projection (permuted W in LDS, 6 outputs/lane, coalesced
//   12B/lane writes); attention kernel computes q + skip inline (one wave per
//   node), online softmax, fused epilogue (mean heads + skip + relu + resid).
//   Layer 3: kv3 staged f32 [n][20]; attn computes q3/s3 inline, fuses
//   skip-add + log_softmax.
// ---------------------------------------------------------------------------

__device__ __forceinline__ float bf2f(u16 u) {
  union { u32 i; float f; } c; c.i = ((u32)u) << 16; return c.f;
}
__device__ __forceinline__ u16 f2bf(float f) {
  union { float f; u32 i; } c; c.f = f;
  u32 u = c.i;
  u32 r = u + 0x7fffu + ((u >> 16) & 1u);  // round-to-nearest-even
  return (u16)(r >> 16);
}

__global__ __launch_bounds__(256) void zero_i32_kernel(int* __restrict__ p, int n) {
  int i = blockIdx.x * blockDim.x + threadIdx.x;
  if (i < n) p[i] = 0;
}

__global__ __launch_bounds__(256) void deg_kernel(
    const int* __restrict__ dst, int* __restrict__ deg, int E) {
  int e = blockIdx.x * blockDim.x + threadIdx.x;
  if (e < E) atomicAdd(&deg[dst[e]], 1);
}

// per-block (1024) exclusive scan; writes per-elem exclusive + block sum
__global__ __launch_bounds__(1024) void scan1_kernel(
    const int* __restrict__ deg, int* __restrict__ excl,
    int* __restrict__ bsum, int n) {
  __shared__ int wsum[16];
  int tid = threadIdx.x;
  int i = blockIdx.x * 1024 + tid;
  int v = (i < n) ? deg[i] : 0;
  int lane = tid & 63, w = tid >> 6;
  int val = v;
#pragma unroll
  for (int off = 1; off < 64; off <<= 1) {
    int t = __shfl_up(val, off, 64);
    if (lane >= off) val += t;
  }
  if (lane == 63) wsum[w] = val;
  __syncthreads();
  if (tid < 16) {
    int xv = wsum[tid];
    int xs = xv;
#pragma unroll
    for (int off = 1; off < 16; off <<= 1) {
      int t = __shfl_up(xs, off, 16);
      if (tid >= off) xs += t;
    }
    wsum[tid] = xs - xv;  // exclusive wave offset
  }
  __syncthreads();
  int incl = val + wsum[w];
  if (i < n) excl[i] = incl - v;
  if (tid == 1023) bsum[blockIdx.x] = incl;
}

// single block: in-place exclusive scan of nb (<=1024) block sums
__global__ __launch_bounds__(1024) void scan2_kernel(int* __restrict__ bsum, int nb) {
  __shared__ int wsum[16];
  int tid = threadIdx.x;
  int v = (tid < nb) ? bsum[tid] : 0;
  int lane = tid & 63, w = tid >> 6;
  int val = v;
#pragma unroll
  for (int off = 1; off < 64; off <<= 1) {
    int t = __shfl_up(val, off, 64);
    if (lane >= off) val += t;
  }
  if (lane == 63) wsum[w] = val;
  __syncthreads();
  if (tid < 16) {
    int xv = wsum[tid];
    int xs = xv;
#pragma unroll
    for (int off = 1; off < 16; off <<= 1) {
      int t = __shfl_up(xs, off, 16);
      if (tid >= off) xs += t;
    }
    wsum[tid] = xs - xv;
  }
  __syncthreads();
  int incl = val + wsum[w];
  if (tid < nb) bsum[tid] = incl - v;
}

__global__ __launch_bounds__(256) void scan3_kernel(
    const int* __restrict__ excl, const int* __restrict__ bsum,
    int* __restrict__ rowptr, int* __restrict__ cursor, int n, int E) {
  int i = blockIdx.x * blockDim.x + threadIdx.x;
  if (i < n) {
    int r = excl[i] + bsum[i >> 10];
    rowptr[i] = r;
    cursor[i] = r;
  }
  if (i == n) rowptr[n] = E;
}

__global__ __launch_bounds__(256) void scatter_kernel(
    const int* __restrict__ src, const int* __restrict__ dst,
    int* __restrict__ cursor, int* __restrict__ csr_src, int E) {
  int e = blockIdx.x * blockDim.x + threadIdx.x;
  if (e < E) {
    int pos = atomicAdd(&cursor[dst[e]], 1);
    csr_src[pos] = src[e];
  }
}

// ---------------------------------------------------------------------------
// kv projection v2: LDS-tiled. Block = 256 threads (4 waves), 32 nodes/block
// (8 per wave). W staged in LDS as bf16 in the PERMUTED interleaved column
// order j = c*6 + which*3 + h  (o = which*192 + h*64 + c), so lane c's 6
// outputs are 12 contiguous LDS bytes per i and 12 contiguous output bytes.
// ---------------------------------------------------------------------------
template<int FI, bool XBF>
__global__ __launch_bounds__(256) void kv_proj_v2(
    const void* __restrict__ xin,
    const float* __restrict__ Wk, const float* __restrict__ bk,
    const float* __restrict__ Wv, const float* __restrict__ bv,
    u16* __restrict__ kv, int n_nodes) {
  __shared__ u16 Wlds[FI * 384];
  __shared__ float blds[384];
  int tid = threadIdx.x;
  for (int idx = tid; idx < FI * 384; idx += 256) {
    int i = idx / 384;
    int j = idx - i * 384;
    int c = j / 6;
    int r = j - c * 6;
    int which = r / 3;         // 0=k 1=v
    int h = r - which * 3;
    int o = h * 64 + c;
    float w = which ? Wv[i * 192 + o] : Wk[i * 192 + o];
    Wlds[idx] = f2bf(w);
  }
  for (int j = tid; j < 384; j += 256) {
    int c = j / 6;
    int r = j - c * 6;
    int which = r / 3;
    int h = r - which * 3;
    int o = h * 64 + c;
    blds[j] = which ? bv[o] : bk[o];
  }
  __syncthreads();
  int wv = tid >> 6, lane = tid & 63;
  float b0 = blds[lane * 6 + 0], b1 = blds[lane * 6 + 1], b2 = blds[lane * 6 + 2];
  float b3 = blds[lane * 6 + 3], b4 = blds[lane * 6 + 4], b5 = blds[lane * 6 + 5];
#pragma unroll
  for (int t = 0; t < 8; ++t) {
    int n = blockIdx.x * 32 + wv * 8 + t;
    if (n >= n_nodes) break;  // wave-uniform
    float a0 = b0, a1 = b1, a2 = b2, a3 = b3, a4 = b4, a5 = b5;
    const u16* xb = (const u16*)xin + (size_t)n * FI;
    const float* xf = (const float*)xin + (size_t)n * FI;
#pragma unroll
    for (int i = 0; i < FI; ++i) {
      float xi = XBF ? bf2f(xb[i]) : xf[i];
      const u32* wr = (const u32*)(Wlds + i * 384 + 6 * lane);
      u32 w01 = wr[0], w23 = wr[1], w45 = wr[2];
      a0 = fmaf(xi, bf2f((u16)w01), a0);
      a1 = fmaf(xi, bf2f((u16)(w01 >> 16)), a1);
      a2 = fmaf(xi, bf2f((u16)w23), a2);
      a3 = fmaf(xi, bf2f((u16)(w23 >> 16)), a3);
      a4 = fmaf(xi, bf2f((u16)w45), a4);
      a5 = fmaf(xi, bf2f((u16)(w45 >> 16)), a5);
    }
    u32* outp = (u32*)(kv + (size_t)n * 384) + 3 * lane;
    outp[0] = (u32)f2bf(a0) | ((u32)f2bf(a1) << 16);
    outp[1] = (u32)f2bf(a2) | ((u32)f2bf(a3) << 16);
    outp[2] = (u32)f2bf(a4) | ((u32)f2bf(a5) << 16);
  }
}

// Fused attention, H=3, C=64, one wave per dst node, q+skip computed inline.
// Gathers bf16 kv (12B contiguous per lane per edge).
template<int FI, bool XBF>
__global__ __launch_bounds__(256) void attn_l12_kernel(
    const void* __restrict__ xin,
    const float* __restrict__ Wq, const float* __restrict__ bq,
    const float* __restrict__ Ws, const float* __restrict__ bs,
    const u16* __restrict__ kv,
    const int* __restrict__ rowptr, const int* __restrict__ csr_src,
    const u16* __restrict__ resid,  // null for layer 1
    u16* __restrict__ hout, int n_nodes) {
  int wid = (blockIdx.x * blockDim.x + threadIdx.x) >> 6;
  int lane = threadIdx.x & 63;
  if (wid >= n_nodes) return;
  // inline q + skip projection for this node
  float q0 = bq[lane], q1 = bq[64 + lane], q2 = bq[128 + lane];
  float sk = bs[lane];
  {
    const u16* xb = (const u16*)xin + (size_t)wid * FI;
    const float* xf = (const float*)xin + (size_t)wid * FI;
#pragma unroll 4
    for (int i = 0; i < FI; ++i) {
      float xi = XBF ? bf2f(xb[i]) : xf[i];
      q0 = fmaf(xi, Wq[i * 192 + lane], q0);
      q1 = fmaf(xi, Wq[i * 192 + 64 + lane], q1);
      q2 = fmaf(xi, Wq[i * 192 + 128 + lane], q2);
      sk = fmaf(xi, Ws[i * 64 + lane], sk);
    }
  }
  const float scale = 0.125f;  // 1/sqrt(64)
  q0 *= scale; q1 *= scale; q2 *= scale;
  float m0 = -INFINITY, m1 = -INFINITY, m2 = -INFINITY;
  float s0 = 0.f, s1 = 0.f, s2 = 0.f;
  float a0 = 0.f, a1 = 0.f, a2 = 0.f;
  int beg = rowptr[wid], end = rowptr[wid + 1];
  int e = beg;
  for (; e + 2 <= end; e += 2) {
    int sa = csr_src[e], sb = csr_src[e + 1];
    const u32* pa = (const u32*)(kv + (size_t)sa * 384) + lane * 3;
    const u32* pb = (const u32*)(kv + (size_t)sb * 384) + lane * 3;
    u32 aw0 = pa[0], aw1 = pa[1], aw2 = pa[2];
    u32 bw0 = pb[0], bw1 = pb[1], bw2 = pb[2];
    float ka0 = bf2f((u16)aw0), ka1 = bf2f((u16)(aw0 >> 16)), ka2 = bf2f((u16)aw1);
    float va0 = bf2f((u16)(aw1 >> 16)), va1 = bf2f((u16)aw2), va2 = bf2f((u16)(aw2 >> 16));
    float kb0 = bf2f((u16)bw0), kb1 = bf2f((u16)(bw0 >> 16)), kb2 = bf2f((u16)bw1);
    float vb0 = bf2f((u16)(bw1 >> 16)), vb1 = bf2f((u16)bw2), vb2 = bf2f((u16)(bw2 >> 16));
    float xa0 = q0 * ka0, xa1 = q1 * ka1, xa2 = q2 * ka2;
    float xb0 = q0 * kb0, xb1 = q1 * kb1, xb2 = q2 * kb2;
#pragma unroll
    for (int off = 32; off >= 1; off >>= 1) {
      xa0 += __shfl_xor(xa0, off, 64);
      xa1 += __shfl_xor(xa1, off, 64);
      xa2 += __shfl_xor(xa2, off, 64);
      xb0 += __shfl_xor(xb0, off, 64);
      xb1 += __shfl_xor(xb1, off, 64);
      xb2 += __shfl_xor(xb2, off, 64);
    }
    float nm, sc, wa, wb;
    nm = fmaxf(fmaxf(m0, xa0), xb0);
    sc = __expf(m0 - nm); wa = __expf(xa0 - nm); wb = __expf(xb0 - nm);
    s0 = s0 * sc + wa + wb; a0 = a0 * sc + wa * va0 + wb * vb0; m0 = nm;
    nm = fmaxf(fmaxf(m1, xa1), xb1);
    sc = __expf(m1 - nm); wa = __expf(xa1 - nm); wb = __expf(xb1 - nm);
    s1 = s1 * sc + wa + wb; a1 = a1 * sc + wa * va1 + wb * vb1; m1 = nm;
    nm = fmaxf(fmaxf(m2, xa2), xb2);
    sc = __expf(m2 - nm); wa = __expf(xa2 - nm); wb = __expf(xb2 - nm);
    s2 = s2 * sc + wa + wb; a2 = a2 * sc + wa * va2 + wb * vb2; m2 = nm;
  }
  if (e < end) {
    int sa = csr_src[e];
    const u32* pa = (const u32*)(kv + (size_t)sa * 384) + lane * 3;
    u32 aw0 = pa[0], aw1 = pa[1], aw2 = pa[2];
    float ka0 = bf2f((u16)aw0), ka1 = bf2f((u16)(aw0 >> 16)), ka2 = bf2f((u16)aw1);
    float va0 = bf2f((u16)(aw1 >> 16)), va1 = bf2f((u16)aw2), va2 = bf2f((u16)(aw2 >> 16));
    float xa0 = q0 * ka0, xa1 = q1 * ka1, xa2 = q2 * ka2;
#pragma unroll
    for (int off = 32; off >= 1; off >>= 1) {
      xa0 += __shfl_xor(xa0, off, 64);
      xa1 += __shfl_xor(xa1, off, 64);
      xa2 += __shfl_xor(xa2, off, 64);
    }
    float nm, sc, wa;
    nm = fmaxf(m0, xa0); sc = __expf(m0 - nm); wa = __expf(xa0 - nm);
    s0 = s0 * sc + wa; a0 = a0 * sc + wa * va0; m0 = nm;
    nm = fmaxf(m1, xa1); sc = __expf(m1 - nm); wa = __expf(xa1 - nm);
    s1 = s1 * sc + wa; a1 = a1 * sc + wa * va1; m1 = nm;
    nm = fmaxf(m2, xa2); sc = __expf(m2 - nm); wa = __expf(xa2 - nm);
    s2 = s2 * sc + wa; a2 = a2 * sc + wa * va2; m2 = nm;
  }
  float val = (a0 / (s0 + 1e-16f) + a1 / (s1 + 1e-16f) + a2 / (s2 + 1e-16f)) *
              (1.0f / 3.0f);
  val += sk;
  val = fmaxf(val, 0.0f);
  if (resid) val += bf2f(resid[(size_t)wid * 64 + lane]);
  hout[(size_t)wid * 64 + lane] = f2bf(val);
}

// layer-3 k/v projection -> f32 kv3 [n][20] = {k(10), v(10)}
__global__ __launch_bounds__(256) void kv3_proj_kernel(
    const u16* __restrict__ h,
    const float* __restrict__ Wk, const float* __restrict__ bk,
    const float* __restrict__ Wv, const float* __restrict__ bv,
    float* __restrict__ kv3, int n_nodes) {
  int idx = blockIdx.x * blockDim.x + threadIdx.x;
  if (idx >= n_nodes * 20) return;
  int n = idx / 20;
  int r = idx - n * 20;
  int which = r / 10;
  int o = r - which * 10;
  const float* W = which ? Wv : Wk;
  float acc = (which ? bv : bk)[o];
  const u16* hr = h + (size_t)n * 64;
#pragma unroll
  for (int i = 0; i < 64; ++i) acc = fmaf(bf2f(hr[i]), W[i * 10 + o], acc);
  kv3[(size_t)n * 20 + which * 10 + o] = acc;
}

// layer-3 attention H=1,C=10 concat + skip + log_softmax; q/skip inline.
// 4 nodes per wave, 16 lanes per node.
__global__ __launch_bounds__(256) void attn_l3_kernel(
    const u16* __restrict__ h,
    const float* __restrict__ Wq, const float* __restrict__ bq,
    const float* __restrict__ Ws, const float* __restrict__ bs,
    const float* __restrict__ kv3,
    const int* __restrict__ rowptr, const int* __restrict__ csr_src,
    float* __restrict__ out, int n_nodes) {
  int tid = blockIdx.x * blockDim.x + threadIdx.x;
  int wid = tid >> 6;
  int lane = threadIdx.x & 63;
  int grp = lane >> 4;
  int sub = lane & 15;
  int n = wid * 4 + grp;
  bool an = (n < n_nodes);
  bool ca = an && (sub < 10);
  float q = 0.f, sk = 0.f;
  if (ca) { q = bq[sub]; sk = bs[sub]; }
  if (an) {
    const u16* hr = h + (size_t)n * 64;
#pragma unroll 4
    for (int i = 0; i < 64; ++i) {
      float xi = bf2f(hr[i]);
      if (sub < 10) {
        q = fmaf(xi, Wq[i * 10 + sub], q);
        sk = fmaf(xi, Ws[i * 10 + sub], sk);
      }
    }
  }
  q *= 0.31622776601683794f;  // 1/sqrt(10)
  float m = -INFINITY, s = 0.f, a = 0.f;
  int beg = 0, end = 0;
  if (an) { beg = rowptr[n]; end = rowptr[n + 1]; }
  for (int e = beg; e < end; ++e) {
    int srcn = csr_src[e];
    float kk = (sub < 10) ? kv3[(size_t)srcn * 20 + sub] : 0.f;
    float vv = (sub < 10) ? kv3[(size_t)srcn * 20 + 10 + sub] : 0.f;
    float p = q * kk;
    p += __shfl_xor(p, 1, 64);
    p += __shfl_xor(p, 2, 64);
    p += __shfl_xor(p, 4, 64);
    p += __shfl_xor(p, 8, 64);
    float nm = fmaxf(m, p);
    float sc = __expf(m - nm);
    float w = __expf(p - nm);
    s = s * sc + w;
    a = a * sc + w * vv;
    m = nm;
  }
  float z = 0.f;
  if (ca) z = a / (s + 1e-16f) + sk;
  float zm = (sub < 10) ? z : -INFINITY;
  float t;
  t = __shfl_xor(zm, 1, 64); zm = fmaxf(zm, t);
  t = __shfl_xor(zm, 2, 64); zm = fmaxf(zm, t);
  t = __shfl_xor(zm, 4, 64); zm = fmaxf(zm, t);
  t = __shfl_xor(zm, 8, 64); zm = fmaxf(zm, t);
  float ez = (sub < 10) ? __expf(z - zm) : 0.f;
  float se = ez;
  se += __shfl_xor(se, 1, 64);
  se += __shfl_xor(se, 2, 64);
  se += __shfl_xor(se, 4, 64);
  se += __shfl_xor(se, 8, 64);
  float ls = logf(se);
  if (ca) out[(size_t)n * 10 + sub] = (z - zm) - ls;
}

extern "C" void kernel_launch(void* const* d_in, const int* in_sizes, int n_in,
                              void* d_out, int out_size, void* d_ws, size_t ws_size,
                              hipStream_t stream) {
  const float* x = (const float*)d_in[0];
  const int* ei = (const int*)d_in[1];
  const int N = in_sizes[0] / 13;
  const int E = in_sizes[1] / 2;
  const int* esrc = ei;
  const int* edst = ei + E;

  const float* q1w = (const float*)d_in[2];  const float* q1b = (const float*)d_in[3];
  const float* k1w = (const float*)d_in[4];  const float* k1b = (const float*)d_in[5];
  const float* v1w = (const float*)d_in[6];  const float* v1b = (const float*)d_in[7];
  const float* s1w = (const float*)d_in[8];  const float* s1b = (const float*)d_in[9];
  const float* q2w = (const float*)d_in[10]; const float* q2b = (const float*)d_in[11];
  const float* k2w = (const float*)d_in[12]; const float* k2b = (const float*)d_in[13];
  const float* v2w = (const float*)d_in[14]; const float* v2b = (const float*)d_in[15];
  const float* s2w = (const float*)d_in[16]; const float* s2b = (const float*)d_in[17];
  const float* q3w = (const float*)d_in[18]; const float* q3b = (const float*)d_in[19];
  const float* k3w = (const float*)d_in[20]; const float* k3b = (const float*)d_in[21];
  const float* v3w = (const float*)d_in[22]; const float* v3b = (const float*)d_in[23];
  const float* s3w = (const float*)d_in[24]; const float* s3b = (const float*)d_in[25];

  // ---- workspace carve-up ----
  size_t off = 0;
  auto carve = [&](size_t bytes) {
    void* p = (char*)d_ws + off;
    off += (bytes + 255) & ~(size_t)255;
    return p;
  };
  int* deg    = (int*)carve((size_t)N * 4);
  int* excl   = (int*)carve((size_t)N * 4);
  int* bsum   = (int*)carve(4096);
  int* rowptr = (int*)carve((size_t)(N + 1) * 4);
  int* cursor = (int*)carve((size_t)N * 4);
  int* csr    = (int*)carve((size_t)E * 4);
  u16* h1     = (u16*)carve((size_t)N * 64 * 2);
  u16* h2     = (u16*)carve((size_t)N * 64 * 2);
  float* kv3  = (float*)carve((size_t)N * 20 * 4);
  u16* kv     = (u16*)carve((size_t)N * 384 * 2);
  if (off > ws_size) return;  // workspace too small — fail loudly

  // ---- CSR build ----
  int nb = (N + 1023) / 1024;
  zero_i32_kernel<<<(N + 255) / 256, 256, 0, stream>>>(deg, N);
  deg_kernel<<<(E + 255) / 256, 256, 0, stream>>>(edst, deg, E);
  scan1_kernel<<<nb, 1024, 0, stream>>>(deg, excl, bsum, N);
  scan2_kernel<<<1, 1024, 0, stream>>>(bsum, nb);
  scan3_kernel<<<(N + 1 + 255) / 256, 256, 0, stream>>>(excl, bsum, rowptr, cursor, N, E);
  scatter_kernel<<<(E + 255) / 256, 256, 0, stream>>>(esrc, edst, cursor, csr, E);

  int attn_blocks = (N + 3) / 4;     // one wave per node, 4 waves per block
  int proj_blocks = (N + 31) / 32;   // 32 nodes per block
  // ---- layer 1: x(f32)[N,13] -> h1(bf16)[N,64] ----
  kv_proj_v2<13, false><<<proj_blocks, 256, 0, stream>>>(
      x, k1w, k1b, v1w, v1b, kv, N);
  attn_l12_kernel<13, false><<<attn_blocks, 256, 0, stream>>>(
      x, q1w, q1b, s1w, s1b, kv, rowptr, csr, nullptr, h1, N);
  // ---- layer 2: h1 -> h2 = relu(conv2(h1)) + h1 ----
  kv_proj_v2<64, true><<<proj_blocks, 256, 0, stream>>>(
      h1, k2w, k2b, v2w, v2b, kv, N);
  attn_l12_kernel<64, true><<<attn_blocks, 256, 0, stream>>>(
      h1, q2w, q2b, s2w, s2b, kv, rowptr, csr, h1, h2, N);
  // ---- layer 3: h2 -> out[N,10] + log_softmax ----
  kv3_proj_kernel<<<(N * 20 + 255) / 256, 256, 0, stream>>>(
      h2, k3w, k3b, v3w, v3b, kv3, N);
  attn_l3_kernel<<<(N + 15) / 16, 256, 0, stream>>>(
      h2, q3w, q3b, s3w, s3b, kv3, rowptr, csr, (float*)d_out, N);
}

// Round 10
// 1299.065 us; speedup vs baseline: 1.3083x; 1.0653x over previous
//
#include <hip/hip_runtime.h>
#include <math.h>

typedef unsigned int u32;
typedef unsigned short u16;

// ---------------------------------------------------------------------------
// Graph TransformerConv x3 (PyG semantics).
//   CSR build (deg -> two-level scan -> scatter), reused by all 3 layers.
//   Per layer: kv staged bf16 in GROUP-PACKED layout (16 lanes per edge,
//   4 channels per lane: slot s: g=s/24, which=(s%24)/12, h=(s%12)/4,
//   cs=s%4, channel=4g+cs) via LDS-tiled projection; attention kernel v3:
//   one wave per dst node, 4 edge-groups of 16 lanes, 2 edges/group/iter,
//   online softmax per group + cross-group merge, epilogue fused.
//   Layer 3: kv3 staged f32 [n][20]; attn computes q3/s3 inline, fuses
//   skip-add + log_softmax.
// ---------------------------------------------------------------------------

__device__ __forceinline__ float bf2f(u16 u) {
  union { u32 i; float f; } c; c.i = ((u32)u) << 16; return c.f;
}
__device__ __forceinline__ u16 f2bf(float f) {
  union { float f; u32 i; } c; c.f = f;
  u32 u = c.i;
  u32 r = u + 0x7fffu + ((u >> 16) & 1u);  // round-to-nearest-even
  return (u16)(r >> 16);
}
__device__ __forceinline__ float blo(u32 w) {
  union { u32 i; float f; } c; c.i = w << 16; return c.f;
}
__device__ __forceinline__ float bhi(u32 w) {
  union { u32 i; float f; } c; c.i = w & 0xffff0000u; return c.f;
}

__global__ __launch_bounds__(256) void zero_i32_kernel(int* __restrict__ p, int n) {
  int i = blockIdx.x * blockDim.x + threadIdx.x;
  if (i < n) p[i] = 0;
}

__global__ __launch_bounds__(256) void deg_kernel(
    const int* __restrict__ dst, int* __restrict__ deg, int E) {
  int e = blockIdx.x * blockDim.x + threadIdx.x;
  if (e < E) atomicAdd(&deg[dst[e]], 1);
}

// per-block (1024) exclusive scan; writes per-elem exclusive + block sum
__global__ __launch_bounds__(1024) void scan1_kernel(
    const int* __restrict__ deg, int* __restrict__ excl,
    int* __restrict__ bsum, int n) {
  __shared__ int wsum[16];
  int tid = threadIdx.x;
  int i = blockIdx.x * 1024 + tid;
  int v = (i < n) ? deg[i] : 0;
  int lane = tid & 63, w = tid >> 6;
  int val = v;
#pragma unroll
  for (int off = 1; off < 64; off <<= 1) {
    int t = __shfl_up(val, off, 64);
    if (lane >= off) val += t;
  }
  if (lane == 63) wsum[w] = val;
  __syncthreads();
  if (tid < 16) {
    int xv = wsum[tid];
    int xs = xv;
#pragma unroll
    for (int off = 1; off < 16; off <<= 1) {
      int t = __shfl_up(xs, off, 16);
      if (tid >= off) xs += t;
    }
    wsum[tid] = xs - xv;  // exclusive wave offset
  }
  __syncthreads();
  int incl = val + wsum[w];
  if (i < n) excl[i] = incl - v;
  if (tid == 1023) bsum[blockIdx.x] = incl;
}

// single block: in-place exclusive scan of nb (<=1024) block sums
__global__ __launch_bounds__(1024) void scan2_kernel(int* __restrict__ bsum, int nb) {
  __shared__ int wsum[16];
  int tid = threadIdx.x;
  int v = (tid < nb) ? bsum[tid] : 0;
  int lane = tid & 63, w = tid >> 6;
  int val = v;
#pragma unroll
  for (int off = 1; off < 64; off <<= 1) {
    int t = __shfl_up(val, off, 64);
    if (lane >= off) val += t;
  }
  if (lane == 63) wsum[w] = val;
  __syncthreads();
  if (tid < 16) {
    int xv = wsum[tid];
    int xs = xv;
#pragma unroll
    for (int off = 1; off < 16; off <<= 1) {
      int t = __shfl_up(xs, off, 16);
      if (tid >= off) xs += t;
    }
    wsum[tid] = xs - xv;
  }
  __syncthreads();
  int incl = val + wsum[w];
  if (tid < nb) bsum[tid] = incl - v;
}

__global__ __launch_bounds__(256) void scan3_kernel(
    const int* __restrict__ excl, const int* __restrict__ bsum,
    int* __restrict__ rowptr, int* __restrict__ cursor, int n, int E) {
  int i = blockIdx.x * blockDim.x + threadIdx.x;
  if (i < n) {
    int r = excl[i] + bsum[i >> 10];
    rowptr[i] = r;
    cursor[i] = r;
  }
  if (i == n) rowptr[n] = E;
}

__global__ __launch_bounds__(256) void scatter_kernel(
    const int* __restrict__ src, const int* __restrict__ dst,
    int* __restrict__ cursor, int* __restrict__ csr_src, int E) {
  int e = blockIdx.x * blockDim.x + threadIdx.x;
  if (e < E) {
    int pos = atomicAdd(&cursor[dst[e]], 1);
    csr_src[pos] = src[e];
  }
}

// ---------------------------------------------------------------------------
// kv projection: LDS-tiled, 32 nodes/block (8 per wave). W staged in LDS bf16
// in the GROUP-PACKED slot order (see header). Lane l accumulates 6 outputs
// from 12 contiguous LDS bytes per i and writes 12 contiguous output bytes.
// ---------------------------------------------------------------------------
template<int FI, bool XBF>
__global__ __launch_bounds__(256) void kv_proj_v2(
    const void* __restrict__ xin,
    const float* __restrict__ Wk, const float* __restrict__ bk,
    const float* __restrict__ Wv, const float* __restrict__ bv,
    u16* __restrict__ kv, int n_nodes) {
  __shared__ u16 Wlds[FI * 384];
  __shared__ float blds[384];
  int tid = threadIdx.x;
  for (int idx = tid; idx < FI * 384; idx += 256) {
    int i = idx / 384;
    int s = idx - i * 384;
    int g = s / 24;
    int r = s - g * 24;
    int which = r / 12;        // 0=k 1=v
    int rr = r - which * 12;
    int h = rr >> 2;
    int cs = rr & 3;
    int o = h * 64 + (g * 4 + cs);
    float w = which ? Wv[i * 192 + o] : Wk[i * 192 + o];
    Wlds[idx] = f2bf(w);
  }
  for (int s = tid; s < 384; s += 256) {
    int g = s / 24;
    int r = s - g * 24;
    int which = r / 12;
    int rr = r - which * 12;
    int h = rr >> 2;
    int cs = rr & 3;
    int o = h * 64 + (g * 4 + cs);
    blds[s] = which ? bv[o] : bk[o];
  }
  __syncthreads();
  int wv = tid >> 6, lane = tid & 63;
  float b0 = blds[lane * 6 + 0], b1 = blds[lane * 6 + 1], b2 = blds[lane * 6 + 2];
  float b3 = blds[lane * 6 + 3], b4 = blds[lane * 6 + 4], b5 = blds[lane * 6 + 5];
#pragma unroll
  for (int t = 0; t < 8; ++t) {
    int n = blockIdx.x * 32 + wv * 8 + t;
    if (n >= n_nodes) break;  // wave-uniform
    float a0 = b0, a1 = b1, a2 = b2, a3 = b3, a4 = b4, a5 = b5;
    const u16* xb = (const u16*)xin + (size_t)n * FI;
    const float* xf = (const float*)xin + (size_t)n * FI;
#pragma unroll
    for (int i = 0; i < FI; ++i) {
      float xi = XBF ? bf2f(xb[i]) : xf[i];
      const u32* wr = (const u32*)(Wlds + i * 384 + 6 * lane);
      u32 w01 = wr[0], w23 = wr[1], w45 = wr[2];
      a0 = fmaf(xi, blo(w01), a0);
      a1 = fmaf(xi, bhi(w01), a1);
      a2 = fmaf(xi, blo(w23), a2);
      a3 = fmaf(xi, bhi(w23), a3);
      a4 = fmaf(xi, blo(w45), a4);
      a5 = fmaf(xi, bhi(w45), a5);
    }
    u32* outp = (u32*)(kv + (size_t)n * 384) + 3 * lane;
    outp[0] = (u32)f2bf(a0) | ((u32)f2bf(a1) << 16);
    outp[1] = (u32)f2bf(a2) | ((u32)f2bf(a3) << 16);
    outp[2] = (u32)f2bf(a4) | ((u32)f2bf(a5) << 16);
  }
}

// ---------------------------------------------------------------------------
// Fused attention v3, H=3, C=64. One wave per dst node; 4 edge-groups of 16
// lanes (lane holds 4 channels); 2 edges per group per iteration. Online
// softmax per group (m init -1e30 sentinel, invalid edges weight 0), then
// cross-group merge via xor-16/32 shuffles. q/skip projected channel-per-lane
// then transposed to packed layout with 16 shuffles.
// ---------------------------------------------------------------------------
template<int FI, bool XBF>
__global__ __launch_bounds__(256) void attn_l12_v3(
    const void* __restrict__ xin,
    const float* __restrict__ Wq, const float* __restrict__ bq,
    const float* __restrict__ Ws, const float* __restrict__ bs,
    const u16* __restrict__ kv,
    const int* __restrict__ rowptr, const int* __restrict__ csr_src,
    const u16* __restrict__ resid,  // null for layer 1
    u16* __restrict__ hout, int n_nodes) {
  int wid = (blockIdx.x * blockDim.x + threadIdx.x) >> 6;
  int lane = threadIdx.x & 63;
  if (wid >= n_nodes) return;
  // ---- q + skip projection, channel-per-lane ----
  float q0 = bq[lane], q1 = bq[64 + lane], q2 = bq[128 + lane];
  float sk = bs[lane];
  {
    const u16* xb = (const u16*)xin + (size_t)wid * FI;
    const float* xf = (const float*)xin + (size_t)wid * FI;
#pragma unroll 4
    for (int i = 0; i < FI; ++i) {
      float xi = XBF ? bf2f(xb[i]) : xf[i];
      q0 = fmaf(xi, Wq[i * 192 + lane], q0);
      q1 = fmaf(xi, Wq[i * 192 + 64 + lane], q1);
      q2 = fmaf(xi, Wq[i * 192 + 128 + lane], q2);
      sk = fmaf(xi, Ws[i * 64 + lane], sk);
    }
  }
  const float scale = 0.125f;  // 1/sqrt(64)
  q0 *= scale; q1 *= scale; q2 *= scale;
  // ---- transpose to packed layout: lane holds channels 4*glane+cs ----
  int glane = lane & 15;
  int grp = lane >> 4;
  float qp[3][4], skp[4];
#pragma unroll
  for (int cs = 0; cs < 4; ++cs) {
    int srcl = 4 * glane + cs;
    qp[0][cs] = __shfl(q0, srcl, 64);
    qp[1][cs] = __shfl(q1, srcl, 64);
    qp[2][cs] = __shfl(q2, srcl, 64);
    skp[cs] = __shfl(sk, srcl, 64);
  }
  float m[3] = {-1e30f, -1e30f, -1e30f};
  float sden[3] = {0.f, 0.f, 0.f};
  float acc[3][4] = {{0.f, 0.f, 0.f, 0.f}, {0.f, 0.f, 0.f, 0.f}, {0.f, 0.f, 0.f, 0.f}};
  int beg = rowptr[wid], end = rowptr[wid + 1];
  int el = end - 1;
  for (int base = beg; base < end; base += 8) {
    int e0 = base + grp * 2;
    int e1 = e0 + 1;
    bool v0 = e0 < end, v1 = e1 < end;
    int sa = csr_src[v0 ? e0 : el];
    int sb = csr_src[v1 ? e1 : el];
    const uint4* pa = (const uint4*)(kv + (size_t)sa * 384 + glane * 24);
    const uint4* pb = (const uint4*)(kv + (size_t)sb * 384 + glane * 24);
    uint4 A0 = pa[0], A1 = pa[1], A2 = pa[2];
    uint4 B0 = pb[0], B1 = pb[1], B2 = pb[2];
    float dA[3], dB[3];
#pragma unroll
    for (int h = 0; h < 3; ++h) {
      u32 ka0 = (h == 0) ? A0.x : (h == 1) ? A0.z : A1.x;
      u32 ka1 = (h == 0) ? A0.y : (h == 1) ? A0.w : A1.y;
      u32 kb0 = (h == 0) ? B0.x : (h == 1) ? B0.z : B1.x;
      u32 kb1 = (h == 0) ? B0.y : (h == 1) ? B0.w : B1.y;
      dA[h] = fmaf(qp[h][0], blo(ka0), fmaf(qp[h][1], bhi(ka0),
              fmaf(qp[h][2], blo(ka1), qp[h][3] * bhi(ka1))));
      dB[h] = fmaf(qp[h][0], blo(kb0), fmaf(qp[h][1], bhi(kb0),
              fmaf(qp[h][2], blo(kb1), qp[h][3] * bhi(kb1))));
    }
    // reduce within the 16-lane group (one instr serves all 4 groups)
#pragma unroll
    for (int off = 1; off <= 8; off <<= 1) {
#pragma unroll
      for (int h = 0; h < 3; ++h) {
        dA[h] += __shfl_xor(dA[h], off, 64);
        dB[h] += __shfl_xor(dB[h], off, 64);
      }
    }
    // online-softmax update (pair-merged), invalid edges contribute 0
#pragma unroll
    for (int h = 0; h < 3; ++h) {
      float pa_ = v0 ? dA[h] : -1e30f;
      float pb_ = v1 ? dB[h] : -1e30f;
      float nm = fmaxf(m[h], fmaxf(pa_, pb_));
      float sc = __expf(m[h] - nm);
      float wa = v0 ? __expf(pa_ - nm) : 0.f;
      float wb = v1 ? __expf(pb_ - nm) : 0.f;
      sden[h] = sden[h] * sc + wa + wb;
      u32 va0 = (h == 0) ? A1.z : (h == 1) ? A2.x : A2.z;
      u32 va1 = (h == 0) ? A1.w : (h == 1) ? A2.y : A2.w;
      u32 vb0 = (h == 0) ? B1.z : (h == 1) ? B2.x : B2.z;
      u32 vb1 = (h == 0) ? B1.w : (h == 1) ? B2.y : B2.w;
      acc[h][0] = fmaf(acc[h][0], sc, fmaf(wa, blo(va0), wb * blo(vb0)));
      acc[h][1] = fmaf(acc[h][1], sc, fmaf(wa, bhi(va0), wb * bhi(vb0)));
      acc[h][2] = fmaf(acc[h][2], sc, fmaf(wa, blo(va1), wb * blo(vb1)));
      acc[h][3] = fmaf(acc[h][3], sc, fmaf(wa, bhi(va1), wb * bhi(vb1)));
      m[h] = nm;
    }
  }
  // ---- merge the 4 group-states (xor 16, then 32) ----
#pragma unroll
  for (int off = 16; off <= 32; off <<= 1) {
#pragma unroll
    for (int h = 0; h < 3; ++h) {
      float mo = __shfl_xor(m[h], off, 64);
      float so = __shfl_xor(sden[h], off, 64);
      float nm = fmaxf(m[h], mo);
      float c1 = __expf(m[h] - nm);
      float c2 = __expf(mo - nm);
      sden[h] = sden[h] * c1 + so * c2;
#pragma unroll
      for (int cs = 0; cs < 4; ++cs) {
        float ao = __shfl_xor(acc[h][cs], off, 64);
        acc[h][cs] = acc[h][cs] * c1 + ao * c2;
      }
      m[h] = nm;
    }
  }
  // ---- epilogue (group 0 writes the 64-channel row) ----
  if (grp == 0) {
    float r0 = 1.f / (sden[0] + 1e-16f);
    float r1 = 1.f / (sden[1] + 1e-16f);
    float r2 = 1.f / (sden[2] + 1e-16f);
    float o_[4];
#pragma unroll
    for (int cs = 0; cs < 4; ++cs) {
      float val = (acc[0][cs] * r0 + acc[1][cs] * r1 + acc[2][cs] * r2) * (1.0f / 3.0f);
      val += skp[cs];
      o_[cs] = fmaxf(val, 0.0f);
    }
    if (resid) {
      uint2 rr = *(const uint2*)(resid + (size_t)wid * 64 + glane * 4);
      o_[0] += blo(rr.x); o_[1] += bhi(rr.x);
      o_[2] += blo(rr.y); o_[3] += bhi(rr.y);
    }
    uint2 pack;
    pack.x = (u32)f2bf(o_[0]) | ((u32)f2bf(o_[1]) << 16);
    pack.y = (u32)f2bf(o_[2]) | ((u32)f2bf(o_[3]) << 16);
    *(uint2*)(hout + (size_t)wid * 64 + glane * 4) = pack;
  }
}

// layer-3 k/v projection -> f32 kv3 [n][20] = {k(10), v(10)}
__global__ __launch_bounds__(256) void kv3_proj_kernel(
    const u16* __restrict__ h,
    const float* __restrict__ Wk, const float* __restrict__ bk,
    const float* __restrict__ Wv, const float* __restrict__ bv,
    float* __restrict__ kv3, int n_nodes) {
  int idx = blockIdx.x * blockDim.x + threadIdx.x;
  if (idx >= n_nodes * 20) return;
  int n = idx / 20;
  int r = idx - n * 20;
  int which = r / 10;
  int o = r - which * 10;
  const float* W = which ? Wv : Wk;
  float acc = (which ? bv : bk)[o];
  const u16* hr = h + (size_t)n * 64;
#pragma unroll
  for (int i = 0; i < 64; ++i) acc = fmaf(bf2f(hr[i]), W[i * 10 + o], acc);
  kv3[(size_t)n * 20 + which * 10 + o] = acc;
}

// layer-3 attention H=1,C=10 concat + skip + log_softmax; q/skip inline.
// 4 nodes per wave, 16 lanes per node.
__global__ __launch_bounds__(256) void attn_l3_kernel(
    const u16* __restrict__ h,
    const float* __restrict__ Wq, const float* __restrict__ bq,
    const float* __restrict__ Ws, const float* __restrict__ bs,
    const float* __restrict__ kv3,
    const int* __restrict__ rowptr, const int* __restrict__ csr_src,
    float* __restrict__ out, int n_nodes) {
  int tid = blockIdx.x * blockDim.x + threadIdx.x;
  int wid = tid >> 6;
  int lane = threadIdx.x & 63;
  int grp = lane >> 4;
  int sub = lane & 15;
  int n = wid * 4 + grp;
  bool an = (n < n_nodes);
  bool ca = an && (sub < 10);
  float q = 0.f, sk = 0.f;
  if (ca) { q = bq[sub]; sk = bs[sub]; }
  if (an) {
    const u16* hr = h + (size_t)n * 64;
#pragma unroll 4
    for (int i = 0; i < 64; ++i) {
      float xi = bf2f(hr[i]);
      if (sub < 10) {
        q = fmaf(xi, Wq[i * 10 + sub], q);
        sk = fmaf(xi, Ws[i * 10 + sub], sk);
      }
    }
  }
  q *= 0.31622776601683794f;  // 1/sqrt(10)
  float m = -INFINITY, s = 0.f, a = 0.f;
  int beg = 0, end = 0;
  if (an) { beg = rowptr[n]; end = rowptr[n + 1]; }
  for (int e = beg; e < end; ++e) {
    int srcn = csr_src[e];
    float kk = (sub < 10) ? kv3[(size_t)srcn * 20 + sub] : 0.f;
    float vv = (sub < 10) ? kv3[(size_t)srcn * 20 + 10 + sub] : 0.f;
    float p = q * kk;
    p += __shfl_xor(p, 1, 64);
    p += __shfl_xor(p, 2, 64);
    p += __shfl_xor(p, 4, 64);
    p += __shfl_xor(p, 8, 64);
    float nm = fmaxf(m, p);
    float sc = __expf(m - nm);
    float w = __expf(p - nm);
    s = s * sc + w;
    a = a * sc + w * vv;
    m = nm;
  }
  float z = 0.f;
  if (ca) z = a / (s + 1e-16f) + sk;
  float zm = (sub < 10) ? z : -INFINITY;
  float t;
  t = __shfl_xor(zm, 1, 64); zm = fmaxf(zm, t);
  t = __shfl_xor(zm, 2, 64); zm = fmaxf(zm, t);
  t = __shfl_xor(zm, 4, 64); zm = fmaxf(zm, t);
  t = __shfl_xor(zm, 8, 64); zm = fmaxf(zm, t);
  float ez = (sub < 10) ? __expf(z - zm) : 0.f;
  float se = ez;
  se += __shfl_xor(se, 1, 64);
  se += __shfl_xor(se, 2, 64);
  se += __shfl_xor(se, 4, 64);
  se += __shfl_xor(se, 8, 64);
  float ls = logf(se);
  if (ca) out[(size_t)n * 10 + sub] = (z - zm) - ls;
}

extern "C" void kernel_launch(void* const* d_in, const int* in_sizes, int n_in,
                              void* d_out, int out_size, void* d_ws, size_t ws_size,
                              hipStream_t stream) {
  const float* x = (const float*)d_in[0];
  const int* ei = (const int*)d_in[1];
  const int N = in_sizes[0] / 13;
  const int E = in_sizes[1] / 2;
  const int* esrc = ei;
  const int* edst = ei + E;

  const float* q1w = (const float*)d_in[2];  const float* q1b = (const float*)d_in[3];
  const float* k1w = (const float*)d_in[4];  const float* k1b = (const float*)d_in[5];
  const float* v1w = (const float*)d_in[6];  const float* v1b = (const float*)d_in[7];
  const float* s1w = (const float*)d_in[8];  const float* s1b = (const float*)d_in[9];
  const float* q2w = (const float*)d_in[10]; const float* q2b = (const float*)d_in[11];
  const float* k2w = (const float*)d_in[12]; const float* k2b = (const float*)d_in[13];
  const float* v2w = (const float*)d_in[14]; const float* v2b = (const float*)d_in[15];
  const float* s2w = (const float*)d_in[16]; const float* s2b = (const float*)d_in[17];
  const float* q3w = (const float*)d_in[18]; const float* q3b = (const float*)d_in[19];
  const float* k3w = (const float*)d_in[20]; const float* k3b = (const float*)d_in[21];
  const float* v3w = (const float*)d_in[22]; const float* v3b = (const float*)d_in[23];
  const float* s3w = (const float*)d_in[24]; const float* s3b = (const float*)d_in[25];

  // ---- workspace carve-up ----
  size_t off = 0;
  auto carve = [&](size_t bytes) {
    void* p = (char*)d_ws + off;
    off += (bytes + 255) & ~(size_t)255;
    return p;
  };
  int* deg    = (int*)carve((size_t)N * 4);
  int* excl   = (int*)carve((size_t)N * 4);
  int* bsum   = (int*)carve(4096);
  int* rowptr = (int*)carve((size_t)(N + 1) * 4);
  int* cursor = (int*)carve((size_t)N * 4);
  int* csr    = (int*)carve((size_t)E * 4);
  u16* h1     = (u16*)carve((size_t)N * 64 * 2);
  u16* h2     = (u16*)carve((size_t)N * 64 * 2);
  float* kv3  = (float*)carve((size_t)N * 20 * 4);
  u16* kv     = (u16*)carve((size_t)N * 384 * 2);
  if (off > ws_size) return;  // workspace too small — fail loudly

  // ---- CSR build ----
  int nb = (N + 1023) / 1024;
  zero_i32_kernel<<<(N + 255) / 256, 256, 0, stream>>>(deg, N);
  deg_kernel<<<(E + 255) / 256, 256, 0, stream>>>(edst, deg, E);
  scan1_kernel<<<nb, 1024, 0, stream>>>(deg, excl, bsum, N);
  scan2_kernel<<<1, 1024, 0, stream>>>(bsum, nb);
  scan3_kernel<<<(N + 1 + 255) / 256, 256, 0, stream>>>(excl, bsum, rowptr, cursor, N, E);
  scatter_kernel<<<(E + 255) / 256, 256, 0, stream>>>(esrc, edst, cursor, csr, E);

  int attn_blocks = (N + 3) / 4;     // one wave per node, 4 waves per block
  int proj_blocks = (N + 31) / 32;   // 32 nodes per block
  // ---- layer 1: x(f32)[N,13] -> h1(bf16)[N,64] ----
  kv_proj_v2<13, false><<<proj_blocks, 256, 0, stream>>>(
      x, k1w, k1b, v1w, v1b, kv, N);
  attn_l12_v3<13, false><<<attn_blocks, 256, 0, stream>>>(
      x, q1w, q1b, s1w, s1b, kv, rowptr, csr, nullptr, h1, N);
  // ---- layer 2: h1 -> h2 = relu(conv2(h1)) + h1 ----
  kv_proj_v2<64, true><<<proj_blocks, 256, 0, stream>>>(
      h1, k2w, k2b, v2w, v2b, kv, N);
  attn_l12_v3<64, true><<<attn_blocks, 256, 0, stream>>>(
      h1, q2w, q2b, s2w, s2b, kv, rowptr, csr, h1, h2, N);
  // ---- layer 3: h2 -> out[N,10] + log_softmax ----
  kv3_proj_kernel<<<(N * 20 + 255) / 256, 256, 0, stream>>>(
      h2, k3w, k3b, v3w, v3b, kv3, N);
  attn_l3_kernel<<<(N + 15) / 16, 256, 0, stream>>>(
      h2, q3w, q3b, s3w, s3b, kv3, rowptr, csr, (float*)d_out, N);
}